// Round 2
// baseline (434.047 us; speedup 1.0000x reference)
//
#include <hip/hip_runtime.h>
#include <hip/hip_cooperative_groups.h>

namespace cg = cooperative_groups;

#define FUZZ 2187
#define NFEAT 7
#define MID 512
#define NCLS 10
#define BATCH 4096
#define SSTR 2192   // padded row stride for S/G (21 rows each)

// ---------------------------------------------------------------------------
// Kernel 1: S[jm][n] = sum over k with IDX[k,j]==m of wei[k*7+j, n]
// k = by*9 + kk, by in [0,243): digits d0..d4 block-uniform (5 register
// accumulators, row picked once at the end); kk in [0,9): d5 = kk/3,
// d6 = kk%3 compile-time accumulator targets. 11 atomics/thread.
// Grid (9, 243) = 2187 blocks = 8748 waves = 34 waves/CU: enough outstanding
// loads to be HBM-BW-bound even if the compiler keeps only ~2 in flight/wave.
// ---------------------------------------------------------------------------
__global__ __launch_bounds__(256) void k_reduce_wei(const float* __restrict__ wei,
                                                    float* __restrict__ S) {
    int n = blockIdx.x * 256 + threadIdx.x;
    if (n >= FUZZ) return;
    int by = blockIdx.y;            // top 5 base-3 digits of k
    int t = by;
    int d4 = t % 3; t /= 3;
    int d3 = t % 3; t /= 3;
    int d2 = t % 3; t /= 3;
    int d1 = t % 3; t /= 3;
    int d0 = t;                     // by < 243
    float a0 = 0.f, a1 = 0.f, a2 = 0.f, a3 = 0.f, a4 = 0.f;
    float h5[3] = {0.f, 0.f, 0.f};
    float h6[3] = {0.f, 0.f, 0.f};
    const float* base = wei + (size_t)(by * 63) * FUZZ + n;
#pragma unroll
    for (int kk = 0; kk < 9; ++kk) {
        const float* rowp = base + (size_t)(kk * 7) * FUZZ;
        float v0 = rowp[0];
        float v1 = rowp[(size_t)1 * FUZZ];
        float v2 = rowp[(size_t)2 * FUZZ];
        float v3 = rowp[(size_t)3 * FUZZ];
        float v4 = rowp[(size_t)4 * FUZZ];
        float v5 = rowp[(size_t)5 * FUZZ];
        float v6 = rowp[(size_t)6 * FUZZ];
        a0 += v0; a1 += v1; a2 += v2; a3 += v3; a4 += v4;
        h5[kk / 3] += v5;
        h6[kk % 3] += v6;
    }
    atomicAdd(&S[(0  + d0) * SSTR + n], a0);
    atomicAdd(&S[(3  + d1) * SSTR + n], a1);
    atomicAdd(&S[(6  + d2) * SSTR + n], a2);
    atomicAdd(&S[(9  + d3) * SSTR + n], a3);
    atomicAdd(&S[(12 + d4) * SSTR + n], a4);
#pragma unroll
    for (int m = 0; m < 3; ++m) {
        atomicAdd(&S[(15 + m) * SSTR + n], h5[m]);
        atomicAdd(&S[(18 + m) * SSTR + n], h6[m]);
    }
}

__device__ __forceinline__ float wave_sum(float v) {
#pragma unroll
    for (int off = 32; off > 0; off >>= 1) v += __shfl_down(v, off, 64);
    return v;
}

// ---------------------------------------------------------------------------
// Fused tail: one cooperative kernel, 512 blocks x 256 threads (2 blocks/CU,
// co-residency guaranteed), 3 grid syncs. Replaces k_sw1 + k_g + k_h + k_out
// whose combined data roofline is ~5 us but which cost ~200 us as 4 serial
// tiny launches.
//   Phase A: SW1[t][i] = sum_n S[t,n]*W1[i,n]; ws1[i] = sum_n W1[i,n]
//            (block per i, 4-wave LDS reduce)
//   Phase B: G[t][n] = sum_i SW1[t,i]*W2[n,i]; q[n]; p[n]  (wave per n)
//   Phase C: H/v/w/T (99 wave-tasks, atomicAdd; zeroed by host memset)
//   Phase D: per-batch epilogue (16 blocks x 256 threads)
// ---------------------------------------------------------------------------
__global__ __launch_bounds__(256) void k_fused_tail(
        const float* __restrict__ S,
        const float* __restrict__ W1,
        const float* __restrict__ b1,
        const float* __restrict__ W2,
        const float* __restrict__ b2,
        const float* __restrict__ W3,
        const float* __restrict__ b3,
        const float* __restrict__ x,
        const float* __restrict__ cc,
        const float* __restrict__ bbv,
        const float* __restrict__ bais,
        float* __restrict__ SW1,
        float* __restrict__ ws1,
        float* __restrict__ G,
        float* __restrict__ q,
        float* __restrict__ p,
        float* __restrict__ T,
        float* __restrict__ H,
        float* __restrict__ v,
        float* __restrict__ w,
        float* __restrict__ out) {
    cg::grid_group grid = cg::this_grid();
    int gid = blockIdx.x;           // 0..511
    int tid = threadIdx.x;
    int wv  = tid >> 6;
    int lane = tid & 63;

    __shared__ float red[4][22];

    // ---------------- Phase A: SW1, ws1 ----------------
    {
        int i = gid;                // exactly 512 blocks
        float acc[21];
        float aw = 0.f;
#pragma unroll
        for (int t = 0; t < 21; ++t) acc[t] = 0.f;
        const float* w1row = W1 + (size_t)i * FUZZ;
        for (int n = tid; n < FUZZ; n += 256) {
            float w1 = w1row[n];
            aw += w1;
#pragma unroll
            for (int t = 0; t < 21; ++t) acc[t] += S[t * SSTR + n] * w1;
        }
#pragma unroll
        for (int t = 0; t < 21; ++t) acc[t] = wave_sum(acc[t]);
        aw = wave_sum(aw);
        if (lane == 0) {
#pragma unroll
            for (int t = 0; t < 21; ++t) red[wv][t] = acc[t];
            red[wv][21] = aw;
        }
        __syncthreads();
        if (tid < 22) {
            float s = red[0][tid] + red[1][tid] + red[2][tid] + red[3][tid];
            if (tid < 21) SW1[tid * MID + i] = s;
            else          ws1[i] = s;
        }
    }
    grid.sync();

    // ---------------- Phase B: G, q, p ----------------
    {
        int gw = gid * 4 + wv;      // 0..2047
        for (int n = gw; n < FUZZ; n += 2048) {
            float acc[21];
            float aq = 0.f, ap = 0.f;
#pragma unroll
            for (int t = 0; t < 21; ++t) acc[t] = 0.f;
            const float* w2row = W2 + (size_t)n * MID;
            for (int i = lane; i < MID; i += 64) {
                float w2 = w2row[i];
                aq += ws1[i] * w2;
                ap += b1[i] * w2;
#pragma unroll
                for (int t = 0; t < 21; ++t) acc[t] += SW1[t * MID + i] * w2;
            }
#pragma unroll
            for (int t = 0; t < 21; ++t) acc[t] = wave_sum(acc[t]);
            aq = wave_sum(aq);
            ap = wave_sum(ap);
            if (lane == 0) {
#pragma unroll
                for (int t = 0; t < 21; ++t) G[t * SSTR + n] = acc[t];
                q[n] = aq;
                p[n] = ap;
            }
        }
    }
    grid.sync();

    // ---------------- Phase C: H, v, w, T ----------------
    {
        int task = gid * 4 + wv;
        if (task < 99) {
            int c = task / 9;       // 0..10
            int chunk = task % 9;
            int n0 = chunk * 243;
            if (c < NCLS) {
                float acc[21];
                float av = 0.f, aw = 0.f;
#pragma unroll
                for (int t = 0; t < 21; ++t) acc[t] = 0.f;
                for (int n = n0 + lane; n < n0 + 243; n += 64) {
                    float w3 = W3[(size_t)c * FUZZ + n];
                    av += (1.0f + q[n]) * w3;
                    aw += (p[n] + b2[n]) * w3;
#pragma unroll
                    for (int t = 0; t < 21; ++t)
                        acc[t] += (S[t * SSTR + n] + G[t * SSTR + n]) * w3;
                }
#pragma unroll
                for (int t = 0; t < 21; ++t) acc[t] = wave_sum(acc[t]);
                av = wave_sum(av);
                aw = wave_sum(aw);
                if (lane == 0) {
#pragma unroll
                    for (int t = 0; t < 21; ++t) atomicAdd(&H[t * NCLS + c], acc[t]);
                    atomicAdd(&v[c], av);
                    atomicAdd(&w[c], aw + (chunk == 0 ? b3[c] : 0.f));
                }
            } else {
                float acc[21];
#pragma unroll
                for (int t = 0; t < 21; ++t) acc[t] = 0.f;
                for (int n = n0 + lane; n < n0 + 243; n += 64) {
#pragma unroll
                    for (int t = 0; t < 21; ++t) acc[t] += S[t * SSTR + n];
                }
#pragma unroll
                for (int t = 0; t < 21; ++t) acc[t] = wave_sum(acc[t]);
                if (lane == 0) {
#pragma unroll
                    for (int t = 0; t < 21; ++t) atomicAdd(&T[t], acc[t]);
                }
            }
        }
    }
    grid.sync();

    // ---------------- Phase D: per-batch epilogue ----------------
    if (gid < 16) {
        int b = gid * 256 + tid;    // 16*256 = 4096 = BATCH
        float xv[NFEAT];
#pragma unroll
        for (int j = 0; j < NFEAT; ++j) xv[j] = x[b * NFEAT + j];
        float u[21];
#pragma unroll
        for (int j = 0; j < NFEAT; ++j) {
#pragma unroll
            for (int m = 0; m < 3; ++m) {
                float d = xv[j] - cc[j * 3 + m];
                float bv = bbv[j * 3 + m];
                u[j * 3 + m] = expf(-(d * d) / (bv * bv));
            }
        }
        float ba = bais[0];
        float r = 2187.0f * ba;
#pragma unroll
        for (int t = 0; t < 21; ++t) r += u[t] * T[t];
        float inv = 1.0f / r;
#pragma unroll
        for (int c = 0; c < NCLS; ++c) {
            float s = 0.f;
#pragma unroll
            for (int t = 0; t < 21; ++t) s += u[t] * H[t * NCLS + c];
            float h = (s + ba * v[c]) * inv + w[c];
            out[b * NCLS + c] = (h >= 0.f) ? h : 0.2f * h;
        }
    }
}

extern "C" void kernel_launch(void* const* d_in, const int* in_sizes, int n_in,
                              void* d_out, int out_size, void* d_ws, size_t ws_size,
                              hipStream_t stream) {
    const float* x    = (const float*)d_in[0];
    const float* c    = (const float*)d_in[1];
    const float* bbv  = (const float*)d_in[2];
    const float* wei  = (const float*)d_in[3];
    const float* bais = (const float*)d_in[4];
    const float* W1   = (const float*)d_in[5];
    const float* b1   = (const float*)d_in[6];
    const float* W2   = (const float*)d_in[7];
    const float* b2   = (const float*)d_in[8];
    const float* W3   = (const float*)d_in[9];
    const float* b3   = (const float*)d_in[10];

    float* ws  = (float*)d_ws;
    float* S   = ws;                         // 21*SSTR
    float* G   = S + 21 * SSTR;              // 21*SSTR
    float* SW1 = G + 21 * SSTR;              // 21*512
    float* ws1 = SW1 + 21 * MID;             // 512
    float* q   = ws1 + MID;                  // SSTR
    float* p   = q + SSTR;                   // SSTR
    float* T   = p + SSTR;                   // 32
    float* H   = T + 32;                     // 224 (21*10 used)
    float* v   = H + 224;                    // 16
    float* w   = v + 16;                     // 16
    float* out = (float*)d_out;

    hipMemsetAsync(S, 0, (size_t)(21 * SSTR) * sizeof(float), stream);
    hipMemsetAsync(T, 0, (size_t)288 * sizeof(float), stream);   // T,H,v,w

    k_reduce_wei<<<dim3(9, 243), 256, 0, stream>>>(wei, S);

    void* args[] = {
        (void*)&S, (void*)&W1, (void*)&b1, (void*)&W2, (void*)&b2,
        (void*)&W3, (void*)&b3, (void*)&x, (void*)&c, (void*)&bbv,
        (void*)&bais, (void*)&SW1, (void*)&ws1, (void*)&G, (void*)&q,
        (void*)&p, (void*)&T, (void*)&H, (void*)&v, (void*)&w, (void*)&out
    };
    hipLaunchCooperativeKernel((const void*)k_fused_tail, dim3(512), dim3(256),
                               args, 0, stream);
}

// Round 3
// 275.220 us; speedup vs baseline: 1.5771x; 1.5771x over previous
//
#include <hip/hip_runtime.h>

#define FUZZ 2187
#define NFEAT 7
#define MID 512
#define NCLS 10
#define BATCH 4096
#define SSTR 2192   // padded row stride for S/G (21 rows each)

// ---------------------------------------------------------------------------
// Kernel 1: S[jm][n] = sum over k with IDX[k,j]==m of wei[k*7+j, n]
// k = by*9 + kk, by in [0,243): digits d0..d4 block-uniform (5 register
// accumulators, row picked once at the end); kk in [0,9): d5 = kk/3,
// d6 = kk%3 compile-time accumulator targets. 11 atomics/thread.
// Grid (9, 243) = 2187 blocks = 8748 waves = 34 waves/CU; 63 independent
// loads per thread -> enough MLP to be HBM-BW-bound (round-1 version at
// (9,81)/27kk was latency-bound: 747 GB/s, VGPR=12).
// ---------------------------------------------------------------------------
__global__ __launch_bounds__(256) void k_reduce_wei(const float* __restrict__ wei,
                                                    float* __restrict__ S) {
    int n = blockIdx.x * 256 + threadIdx.x;
    if (n >= FUZZ) return;
    int by = blockIdx.y;            // top 5 base-3 digits of k
    int t = by;
    int d4 = t % 3; t /= 3;
    int d3 = t % 3; t /= 3;
    int d2 = t % 3; t /= 3;
    int d1 = t % 3; t /= 3;
    int d0 = t;                     // by < 243
    float a0 = 0.f, a1 = 0.f, a2 = 0.f, a3 = 0.f, a4 = 0.f;
    float h5[3] = {0.f, 0.f, 0.f};
    float h6[3] = {0.f, 0.f, 0.f};
    const float* base = wei + (size_t)(by * 63) * FUZZ + n;
#pragma unroll
    for (int kk = 0; kk < 9; ++kk) {
        const float* rowp = base + (size_t)(kk * 7) * FUZZ;
        float v0 = rowp[0];
        float v1 = rowp[(size_t)1 * FUZZ];
        float v2 = rowp[(size_t)2 * FUZZ];
        float v3 = rowp[(size_t)3 * FUZZ];
        float v4 = rowp[(size_t)4 * FUZZ];
        float v5 = rowp[(size_t)5 * FUZZ];
        float v6 = rowp[(size_t)6 * FUZZ];
        a0 += v0; a1 += v1; a2 += v2; a3 += v3; a4 += v4;
        h5[kk / 3] += v5;
        h6[kk % 3] += v6;
    }
    atomicAdd(&S[(0  + d0) * SSTR + n], a0);
    atomicAdd(&S[(3  + d1) * SSTR + n], a1);
    atomicAdd(&S[(6  + d2) * SSTR + n], a2);
    atomicAdd(&S[(9  + d3) * SSTR + n], a3);
    atomicAdd(&S[(12 + d4) * SSTR + n], a4);
#pragma unroll
    for (int m = 0; m < 3; ++m) {
        atomicAdd(&S[(15 + m) * SSTR + n], h5[m]);
        atomicAdd(&S[(18 + m) * SSTR + n], h6[m]);
    }
}

__device__ __forceinline__ float wave_sum(float v) {
#pragma unroll
    for (int off = 32; off > 0; off >>= 1) v += __shfl_down(v, off, 64);
    return v;
}

// ---------------------------------------------------------------------------
// Kernel 2: SW1[jm][i] = sum_n S[jm,n]*W1[i,n];  ws1[i] = sum_n W1[i,n]
// One block (4 waves) per i; n-range split across waves, LDS reduce.
// ---------------------------------------------------------------------------
__global__ __launch_bounds__(256) void k_sw1(const float* __restrict__ S,
                                             const float* __restrict__ W1,
                                             float* __restrict__ SW1,
                                             float* __restrict__ ws1) {
    int i = blockIdx.x;
    int tid = threadIdx.x;
    float acc[21];
    float aw = 0.f;
#pragma unroll
    for (int t = 0; t < 21; ++t) acc[t] = 0.f;
    const float* w1row = W1 + (size_t)i * FUZZ;
    for (int n = tid; n < FUZZ; n += 256) {
        float w1 = w1row[n];
        aw += w1;
#pragma unroll
        for (int t = 0; t < 21; ++t) acc[t] += S[t * SSTR + n] * w1;
    }
#pragma unroll
    for (int t = 0; t < 21; ++t) acc[t] = wave_sum(acc[t]);
    aw = wave_sum(aw);
    __shared__ float red[4][22];
    int w = tid >> 6, lane = tid & 63;
    if (lane == 0) {
#pragma unroll
        for (int t = 0; t < 21; ++t) red[w][t] = acc[t];
        red[w][21] = aw;
    }
    __syncthreads();
    if (tid < 22) {
        float s = red[0][tid] + red[1][tid] + red[2][tid] + red[3][tid];
        if (tid < 21) SW1[tid * MID + i] = s;
        else          ws1[i] = s;
    }
}

// ---------------------------------------------------------------------------
// Kernel 3: G[jm][n] = sum_i SW1[jm,i]*W2[n,i];  q[n] = sum_i ws1[i]*W2[n,i];
//           p[n] = sum_i b1[i]*W2[n,i].  One block (2 waves) per n.
// Block 0 additionally zeroes the 288-float T/H/v/w region (consumed by
// k_h's atomicAdds in the NEXT dispatch) -> saves a memset dispatch.
// ---------------------------------------------------------------------------
__global__ __launch_bounds__(128) void k_g(const float* __restrict__ SW1,
                                           const float* __restrict__ ws1,
                                           const float* __restrict__ b1,
                                           const float* __restrict__ W2,
                                           float* __restrict__ G,
                                           float* __restrict__ q,
                                           float* __restrict__ p,
                                           float* __restrict__ THvw) {
    int n = blockIdx.x;
    int tid = threadIdx.x;
    if (n == 0 && tid < 128) {      // zero T(32)+H(224)+v(16)+w(16) = 288
        THvw[tid] = 0.f;
        THvw[tid + 128] = 0.f;
        if (tid < 32) THvw[tid + 256] = 0.f;
    }
    float acc[21];
    float aq = 0.f, ap = 0.f;
#pragma unroll
    for (int t = 0; t < 21; ++t) acc[t] = 0.f;
    const float* w2row = W2 + (size_t)n * MID;
    for (int i = tid; i < MID; i += 128) {
        float w2 = w2row[i];
        aq += ws1[i] * w2;
        ap += b1[i] * w2;
#pragma unroll
        for (int t = 0; t < 21; ++t) acc[t] += SW1[t * MID + i] * w2;
    }
#pragma unroll
    for (int t = 0; t < 21; ++t) acc[t] = wave_sum(acc[t]);
    aq = wave_sum(aq);
    ap = wave_sum(ap);
    __shared__ float red[2][23];
    int w = tid >> 6, lane = tid & 63;
    if (lane == 0) {
#pragma unroll
        for (int t = 0; t < 21; ++t) red[w][t] = acc[t];
        red[w][21] = aq;
        red[w][22] = ap;
    }
    __syncthreads();
    if (tid < 23) {
        float s = red[0][tid] + red[1][tid];
        if (tid < 21)      G[tid * SSTR + n] = s;
        else if (tid == 21) q[n] = s;
        else                p[n] = s;
    }
}

// ---------------------------------------------------------------------------
// Kernel 4: H[jm][c] = sum_n (S+G)[jm,n]*W3[c,n]
//           v[c] = sum_n (1+q[n])*W3[c,n]
//           w[c] = sum_n (p[n]+b2[n])*W3[c,n] + b3[c]
//           T[jm] = sum_n S[jm,n]              (blockIdx.x == 10)
// Grid (11, 27): n split into 27 chunks of 81, atomicAdd epilogue.
// 297 waves (was 99).
// ---------------------------------------------------------------------------
__global__ __launch_bounds__(64) void k_h(const float* __restrict__ S,
                                          const float* __restrict__ G,
                                          const float* __restrict__ q,
                                          const float* __restrict__ p,
                                          const float* __restrict__ b2,
                                          const float* __restrict__ b3,
                                          const float* __restrict__ W3,
                                          float* __restrict__ H,
                                          float* __restrict__ v,
                                          float* __restrict__ w,
                                          float* __restrict__ T) {
    int c = blockIdx.x;
    int chunk = blockIdx.y;
    int lane = threadIdx.x;
    int n0 = chunk * 81;
    if (c < NCLS) {
        float acc[21];
        float av = 0.f, aw = 0.f;
#pragma unroll
        for (int t = 0; t < 21; ++t) acc[t] = 0.f;
        for (int n = n0 + lane; n < n0 + 81; n += 64) {
            float w3 = W3[(size_t)c * FUZZ + n];
            av += (1.0f + q[n]) * w3;
            aw += (p[n] + b2[n]) * w3;
#pragma unroll
            for (int t = 0; t < 21; ++t)
                acc[t] += (S[t * SSTR + n] + G[t * SSTR + n]) * w3;
        }
#pragma unroll
        for (int t = 0; t < 21; ++t) acc[t] = wave_sum(acc[t]);
        av = wave_sum(av);
        aw = wave_sum(aw);
        if (lane == 0) {
#pragma unroll
            for (int t = 0; t < 21; ++t) atomicAdd(&H[t * NCLS + c], acc[t]);
            atomicAdd(&v[c], av);
            atomicAdd(&w[c], aw + (chunk == 0 ? b3[c] : 0.f));
        }
    } else {
        float acc[21];
#pragma unroll
        for (int t = 0; t < 21; ++t) acc[t] = 0.f;
        for (int n = n0 + lane; n < n0 + 81; n += 64) {
#pragma unroll
            for (int t = 0; t < 21; ++t) acc[t] += S[t * SSTR + n];
        }
#pragma unroll
        for (int t = 0; t < 21; ++t) acc[t] = wave_sum(acc[t]);
        if (lane == 0) {
#pragma unroll
            for (int t = 0; t < 21; ++t) atomicAdd(&T[t], acc[t]);
        }
    }
}

// ---------------------------------------------------------------------------
// Kernel 5: per-batch epilogue. 64 blocks x 64 threads spreads across CUs.
// ---------------------------------------------------------------------------
__global__ __launch_bounds__(64) void k_out(const float* __restrict__ x,
                                            const float* __restrict__ cc,
                                            const float* __restrict__ bbv,
                                            const float* __restrict__ bais,
                                            const float* __restrict__ T,
                                            const float* __restrict__ H,
                                            const float* __restrict__ v,
                                            const float* __restrict__ w,
                                            float* __restrict__ out) {
    int b = blockIdx.x * 64 + threadIdx.x;
    if (b >= BATCH) return;
    float xv[NFEAT];
#pragma unroll
    for (int j = 0; j < NFEAT; ++j) xv[j] = x[b * NFEAT + j];
    float u[21];
#pragma unroll
    for (int j = 0; j < NFEAT; ++j) {
#pragma unroll
        for (int m = 0; m < 3; ++m) {
            float d = xv[j] - cc[j * 3 + m];
            float bv = bbv[j * 3 + m];
            u[j * 3 + m] = expf(-(d * d) / (bv * bv));
        }
    }
    float ba = bais[0];
    float r = 2187.0f * ba;
#pragma unroll
    for (int t = 0; t < 21; ++t) r += u[t] * T[t];
    float inv = 1.0f / r;
#pragma unroll
    for (int c = 0; c < NCLS; ++c) {
        float s = 0.f;
#pragma unroll
        for (int t = 0; t < 21; ++t) s += u[t] * H[t * NCLS + c];
        float h = (s + ba * v[c]) * inv + w[c];
        out[b * NCLS + c] = (h >= 0.f) ? h : 0.2f * h;
    }
}

extern "C" void kernel_launch(void* const* d_in, const int* in_sizes, int n_in,
                              void* d_out, int out_size, void* d_ws, size_t ws_size,
                              hipStream_t stream) {
    const float* x    = (const float*)d_in[0];
    const float* c    = (const float*)d_in[1];
    const float* bbv  = (const float*)d_in[2];
    const float* wei  = (const float*)d_in[3];
    const float* bais = (const float*)d_in[4];
    const float* W1   = (const float*)d_in[5];
    const float* b1   = (const float*)d_in[6];
    const float* W2   = (const float*)d_in[7];
    const float* b2   = (const float*)d_in[8];
    const float* W3   = (const float*)d_in[9];
    const float* b3   = (const float*)d_in[10];

    float* ws  = (float*)d_ws;
    float* S   = ws;                         // 21*SSTR
    float* G   = S + 21 * SSTR;              // 21*SSTR
    float* SW1 = G + 21 * SSTR;              // 21*512
    float* ws1 = SW1 + 21 * MID;             // 512
    float* q   = ws1 + MID;                  // SSTR
    float* p   = q + SSTR;                   // SSTR
    float* T   = p + SSTR;                   // 32  (T,H,v,w contiguous: 288)
    float* H   = T + 32;                     // 224 (21*10 used)
    float* v   = H + 224;                    // 16
    float* w   = v + 16;                     // 16

    hipMemsetAsync(S, 0, (size_t)(21 * SSTR) * sizeof(float), stream);
    k_reduce_wei<<<dim3(9, 243), 256, 0, stream>>>(wei, S);
    k_sw1<<<MID, 256, 0, stream>>>(S, W1, SW1, ws1);
    k_g<<<FUZZ, 128, 0, stream>>>(SW1, ws1, b1, W2, G, q, p, T);
    k_h<<<dim3(NCLS + 1, 27), 64, 0, stream>>>(S, G, q, p, b2, b3, W3, H, v, w, T);
    k_out<<<(BATCH + 63) / 64, 64, 0, stream>>>(x, c, bbv, bais, T, H, v, w,
                                                (float*)d_out);
}